// Round 1
// baseline (573.430 us; speedup 1.0000x reference)
//
#include <hip/hip_runtime.h>
#include <hip/hip_bf16.h>

typedef __bf16 bf16;
typedef __attribute__((ext_vector_type(8))) __bf16 bf16x8;
typedef __attribute__((ext_vector_type(4))) float f32x4;

constexpr int SLEN = 2048;
constexpr int DH = 64;
constexpr int NBH = 64;                      // B*H = 4*16
constexpr float SCALE_LOG2E = 0.125f * 1.4426950408889634f;  // (1/sqrt(64)) * log2(e)

// ---- pre-pass 1: K fp32 -> bf16, 8 elems/thread, fully coalesced ----
__global__ void cast_k_kernel(const float* __restrict__ in, bf16* __restrict__ out) {
    size_t i = (size_t)blockIdx.x * blockDim.x + threadIdx.x;
    const float4* p = (const float4*)in + i * 2;
    float4 a = p[0], b = p[1];
    bf16x8 v;
    v[0]=(bf16)a.x; v[1]=(bf16)a.y; v[2]=(bf16)a.z; v[3]=(bf16)a.w;
    v[4]=(bf16)b.x; v[5]=(bf16)b.y; v[6]=(bf16)b.z; v[7]=(bf16)b.w;
    ((bf16x8*)out)[i] = v;
}

// ---- pre-pass 2: V fp32 [bh][s][d] -> bf16 Vt [bh][d][s] (LDS tile transpose) ----
__global__ void transpose_v_kernel(const float* __restrict__ V, bf16* __restrict__ Vt) {
    __shared__ float t[64][65];
    int bh = blockIdx.y;
    int s0 = blockIdx.x * 64;
    int tx = threadIdx.x & 63, ty = threadIdx.x >> 6;
    const float* vp = V + ((size_t)bh * SLEN + s0) * DH;
    #pragma unroll
    for (int r = ty; r < 64; r += 4) t[r][tx] = vp[(size_t)r * DH + tx];
    __syncthreads();
    bf16* op = Vt + (size_t)bh * DH * SLEN + s0;
    #pragma unroll
    for (int r = ty; r < 64; r += 4) op[(size_t)r * SLEN + tx] = (bf16)t[tx][r];
}

// ---- main attention kernel ----
// Block = 256 threads (4 waves), 64 q-rows per block (16 per wave), k-tiles of 64.
// No online softmax: masked_fill is with 0 (not -inf) and |s|<=~6.3, so exp() is
// safe unnormalized; divide by the row-sum once at the end.
__global__ __launch_bounds__(256) void attn_kernel(
    const float* __restrict__ Q, const int* __restrict__ mask,
    const bf16* __restrict__ Kb, const bf16* __restrict__ Vtb,
    float* __restrict__ out)
{
    __shared__ bf16 P_lds[64][72];   // +8 pad: b128 row reads land 2-way (free)
    const int bh = blockIdx.y;
    const int qbase = blockIdx.x * 64;
    const int tid = threadIdx.x;
    const int w = tid >> 6, l = tid & 63;
    const int lq = l & 15, lg = l >> 4;

    // Q A-frags (row = lq, k = t*32 + lg*8 + j), hoisted; inline fp32->bf16
    bf16x8 aq[2];
    {
        const float* qp = Q + ((size_t)bh * SLEN + qbase + w * 16 + lq) * DH + lg * 8;
        #pragma unroll
        for (int t = 0; t < 2; ++t) {
            float4 x = *(const float4*)(qp + t * 32);
            float4 y = *(const float4*)(qp + t * 32 + 4);
            bf16x8 f;
            f[0]=(bf16)x.x; f[1]=(bf16)x.y; f[2]=(bf16)x.z; f[3]=(bf16)x.w;
            f[4]=(bf16)y.x; f[5]=(bf16)y.y; f[6]=(bf16)y.z; f[7]=(bf16)y.w;
            aq[t] = f;
        }
    }

    f32x4 acc[4] = {{0,0,0,0},{0,0,0,0},{0,0,0,0},{0,0,0,0}}; // ctx[16q][64d], d-subtile n
    float denom[4] = {0.f, 0.f, 0.f, 0.f};                    // rows lg*4+i

    const bf16* kp = Kb  + (size_t)bh * SLEN * DH;
    const bf16* vp = Vtb + (size_t)bh * DH * SLEN;
    const int*  mp = mask + ((size_t)bh * SLEN + qbase + w * 16) * SLEN;

    for (int kb = 0; kb < SLEN; kb += 64) {
        // ---- QK^T: 4 n-subtiles of 16 k-cols, K-dim 64 as 2 MFMAs ----
        #pragma unroll
        for (int n = 0; n < 4; ++n) {
            f32x4 s = {0, 0, 0, 0};
            #pragma unroll
            for (int t = 0; t < 2; ++t) {
                bf16x8 bk = *(const bf16x8*)(kp + (size_t)(kb + n * 16 + lq) * DH + t * 32 + lg * 8);
                s = __builtin_amdgcn_mfma_f32_16x16x32_bf16(aq[t], bk, s, 0, 0, 0);
            }
            // mask + exp (masked score -> 0 -> weight exp(0)=1), accumulate denom, stage P
            #pragma unroll
            for (int i = 0; i < 4; ++i) {
                int m = __builtin_nontemporal_load(mp + (size_t)(lg * 4 + i) * SLEN + kb + n * 16 + lq);
                float e = m ? 0.0f : s[i] * SCALE_LOG2E;
                float p = exp2f(e);
                denom[i] += p;
                P_lds[w * 16 + lg * 4 + i][n * 16 + lq] = (bf16)p;
            }
        }
        // ---- PV: ctx += P(16x64) * V(64x64); P via LDS (same-wave rows only,
        //      same-wave DS ordering => no barrier needed) ----
        #pragma unroll
        for (int n = 0; n < 4; ++n) {
            #pragma unroll
            for (int kk = 0; kk < 2; ++kk) {
                bf16x8 ap = *(const bf16x8*)(&P_lds[w * 16 + lq][kk * 32 + lg * 8]);
                bf16x8 bv = *(const bf16x8*)(vp + (size_t)(n * 16 + lq) * SLEN + kb + kk * 32 + lg * 8);
                acc[n] = __builtin_amdgcn_mfma_f32_16x16x32_bf16(ap, bv, acc[n], 0, 0, 0);
            }
        }
    }

    // denom: reduce across the 16 lanes sharing the same 4 rows (lanes lg*16..lg*16+15)
    #pragma unroll
    for (int i = 0; i < 4; ++i) {
        float d = denom[i];
        #pragma unroll
        for (int mth = 1; mth < 16; mth <<= 1) d += __shfl_xor(d, mth, 64);
        denom[i] = 1.0f / d;
    }

    float* op = out + ((size_t)bh * SLEN + qbase + w * 16) * DH;
    #pragma unroll
    for (int n = 0; n < 4; ++n) {
        #pragma unroll
        for (int i = 0; i < 4; ++i)
            op[(size_t)(lg * 4 + i) * DH + n * 16 + lq] = acc[n][i] * denom[i];
    }
}

extern "C" void kernel_launch(void* const* d_in, const int* in_sizes, int n_in,
                              void* d_out, int out_size, void* d_ws, size_t ws_size,
                              hipStream_t stream) {
    const float* Q    = (const float*)d_in[0];
    const float* K    = (const float*)d_in[1];
    const float* V    = (const float*)d_in[2];
    const int*   mask = (const int*)d_in[3];
    float* out = (float*)d_out;

    // workspace: Kb (16 MB bf16) + Vt (16 MB bf16, d-major)
    bf16* Kb  = (bf16*)d_ws;
    bf16* Vtb = Kb + (size_t)NBH * SLEN * DH;

    int n8 = NBH * SLEN * DH / 8;  // 2,097,152 groups of 8 -> 8192 blocks exactly
    cast_k_kernel<<<n8 / 256, 256, 0, stream>>>(K, Kb);
    transpose_v_kernel<<<dim3(SLEN / 64, NBH), 256, 0, stream>>>(V, Vtb);
    attn_kernel<<<dim3(SLEN / 64, NBH), 256, 0, stream>>>(Q, mask, Kb, Vtb, out);
}